// Round 6
// baseline (4183.878 us; speedup 1.0000x reference)
//
#include <hip/hip_runtime.h>

typedef unsigned short u16;
typedef unsigned int   u32;
typedef unsigned long long u64;
typedef _Float16       f16;

#define B_SZ 2048
#define S_SZ 1024
#define N3   3072
#define F_SZ 50
#define GRID 768

typedef f16    f16x8 __attribute__((ext_vector_type(8)));
typedef f16    f16x4 __attribute__((ext_vector_type(4)));
typedef float  f32x4 __attribute__((ext_vector_type(4)));
typedef u32    u32x4 __attribute__((ext_vector_type(4)));

#define AGENT __HIP_MEMORY_SCOPE_AGENT

// async global->LDS, 16B per lane; LDS dest = base + lane*16 (wave-uniform base)
__device__ __forceinline__ void glds16(const void* g, void* l) {
    __builtin_amdgcn_global_load_lds(
        (const __attribute__((address_space(1))) u32*)g,
        (__attribute__((address_space(3))) u32*)l, 16, 0, 0);
}

// ---------------------------------------------------------------------------
// Mx[2][3072] = W_emb @ W_gru[0:1024, :]  (split-K + atomics; Mx pre-zeroed)
__global__ __launch_bounds__(256) void make_mx(
    const float* __restrict__ We, const float* __restrict__ Wg,
    float* __restrict__ Mx)
{
    int j  = blockIdx.x * 256 + threadIdx.x;
    int k0 = blockIdx.y * 64;
    float s0 = 0.f, s1 = 0.f;
    #pragma unroll 4
    for (int k = k0; k < k0 + 64; k++) {
        float w = Wg[(size_t)k * N3 + j];
        s0 += We[k] * w;
        s1 += We[S_SZ + k] * w;
    }
    atomicAdd(&Mx[j], s0);
    atomicAdd(&Mx[N3 + j], s1);
}

// ---------------------------------------------------------------------------
// Wt[n][k] = fp16(W_gru[1024+k][n])
__global__ __launch_bounds__(256) void transpose_w(
    const float* __restrict__ Wg, f16* __restrict__ Wt)
{
    __shared__ float tile[32][33];
    int n0 = blockIdx.x * 32, k0 = blockIdx.y * 32;
    int c = threadIdx.x & 31, r = threadIdx.x >> 5;
    #pragma unroll
    for (int s = 0; s < 4; s++) {
        int rr = r + s * 8;
        tile[rr][c] = Wg[(size_t)(S_SZ + k0 + rr) * N3 + n0 + c];
    }
    __syncthreads();
    #pragma unroll
    for (int s = 0; s < 4; s++) {
        int rr = r + s * 8;
        Wt[(size_t)(n0 + rr) * S_SZ + k0 + c] = (f16)tile[c][rr];
    }
}

// ---------------------------------------------------------------------------
// Persistent dataflow GRU loop.
// 768 blocks = 32 m-groups (M: 64 rows) x 24 n-tiles (NB: 128 cols).
// Shared mutable data (parts, hh) ONLY via agent-scope (sc1) atomics ->
// coherent at L3, no cache-inv fences, Wt stays L2-resident.
__global__ __launch_bounds__(256, 3) void fused_loop(
    const f16* __restrict__ Wt,     // [3072][1024] fp16 (read-only, L2)
    f16* __restrict__ hh,           // [2048][1024] fp16 state (sc1 only)
    const float* __restrict__ Mx,   // [2][3072]
    const float* __restrict__ act,  // [2048][50][2]
    const float* __restrict__ gamma,
    const float* __restrict__ beta,
    f16* __restrict__ parts,        // [2048][3072] f16 (sc1 only)
    float* __restrict__ hout,       // d_out h region (written at t=49)
    int* __restrict__ cnt)          // gcnt = cnt[M*16], dcnt = cnt[512+M*16]
{
    __shared__ __align__(16) f16 As[64 * 64];    // 8 KB
    __shared__ __align__(16) f16 Bs[128 * 64];   // 16 KB (also epilogue tile)

    const int blk = blockIdx.x;
    const int x8  = blk & 7;            // XCD hint (blockIdx % 8 heuristic)
    const int r   = blk >> 3;           // 0..95
    const int NB  = x8 * 3 + (r % 3);   // 0..23  (each XCD: 3 Wt slices)
    const int M   = r / 3;              // 0..31
    const int m0 = M * 64, n0 = NB * 128;

    const int tid  = threadIdx.x;
    const int lane = tid & 63;
    const int wave = tid >> 6;
    const int wr = (wave >> 1) * 32;
    const int wc = (wave & 1) * 64;
    const int quad = lane >> 4, lrow = lane & 15;
    const int swz = (lrow & 7) * 8;

    // B staging (glds16): per wave 4 chunks of 8 rows x 64 cols
    const int lrow8 = lane >> 3;
    const int scolh = ((lane & 7) * 8) ^ (lrow8 * 8);

    // A staging (sc1 loads -> regs -> LDS, swizzled 8-f16 granules)
    const int arow = tid >> 2;          // 0..63
    const int agi  = (tid & 3) * 2;     // granule pair base (0,2,4,6)
    const int ar7  = arow & 7;

    // epilogue readback/store geometry
    const int erow = tid >> 2;          // 0..63
    const int eseg = (tid & 3) * 32;    // 32 f16 = 64 B per thread

    int* gcnt = cnt + M * 16;
    int* dcnt = cnt + 512 + M * 16;
    const int doLN = (NB % 3) != 2;                 // 16 LN blocks per group
    const int li   = (NB / 3) * 2 + (NB % 3);       // 0..15
    const int lnrow = m0 + li * 4 + wave;           // this wave's LN row

    // preload Mx for epilogue (4 n per thread)
    float mx0[4], mx1[4];
    #pragma unroll
    for (int j = 0; j < 4; j++) {
        int n = n0 + wc + j * 16 + lrow;
        mx0[j] = Mx[n]; mx1[j] = Mx[N3 + n];
    }

    for (int t = 0; t < F_SZ; t++) {
        // wait: LN(t-1) done for group M (hh rows M final)
        if (tid == 0) {
            int tgt = 16 * t;
            while (__hip_atomic_load(dcnt, __ATOMIC_RELAXED, AGENT) < tgt)
                __builtin_amdgcn_s_sleep(2);
        }
        __syncthreads();

        f32x4 acc[2][4];
        #pragma unroll
        for (int i = 0; i < 2; i++)
            #pragma unroll
            for (int j = 0; j < 4; j++)
                acc[i][j] = (f32x4){0.f, 0.f, 0.f, 0.f};

        for (int kb = 0; kb < S_SZ; kb += 64) {
            __syncthreads();
            {   // A: 4 u64 sc1 loads -> 4 swizzled LDS granule-half writes
                const u64* src = (const u64*)(hh + (size_t)(m0 + arow) * S_SZ + kb)
                                 + (size_t)(tid & 3) * 4;
                u64 d0 = __hip_atomic_load(src + 0, __ATOMIC_RELAXED, AGENT);
                u64 d1 = __hip_atomic_load(src + 1, __ATOMIC_RELAXED, AGENT);
                u64 d2 = __hip_atomic_load(src + 2, __ATOMIC_RELAXED, AGENT);
                u64 d3 = __hip_atomic_load(src + 3, __ATOMIC_RELAXED, AGENT);
                *(u64*)&As[arow * 64 + ((agi    ) ^ ar7) * 8    ] = d0;
                *(u64*)&As[arow * 64 + ((agi    ) ^ ar7) * 8 + 4] = d1;
                *(u64*)&As[arow * 64 + ((agi + 1) ^ ar7) * 8    ] = d2;
                *(u64*)&As[arow * 64 + ((agi + 1) ^ ar7) * 8 + 4] = d3;
            }
            #pragma unroll
            for (int c = 0; c < 4; c++) {   // B: glds16, 16 chunks / 4 waves
                int ch = wave * 4 + c;
                int row = ch * 8 + lrow8;
                glds16(&Wt[(size_t)(n0 + row) * S_SZ + kb + scolh], &Bs[ch * 512]);
            }
            __syncthreads();
            #pragma unroll
            for (int kk = 0; kk < 64; kk += 32) {
                f16x8 a[2], b[4];
                #pragma unroll
                for (int i = 0; i < 2; i++)
                    a[i] = __builtin_bit_cast(f16x8,
                        *(const u32x4*)&As[(wr + i * 16 + lrow) * 64 +
                                           ((kk + quad * 8) ^ swz)]);
                #pragma unroll
                for (int j = 0; j < 4; j++)
                    b[j] = __builtin_bit_cast(f16x8,
                        *(const u32x4*)&Bs[(wc + j * 16 + lrow) * 64 +
                                           ((kk + quad * 8) ^ swz)]);
                #pragma unroll
                for (int i = 0; i < 2; i++)
                    #pragma unroll
                    for (int j = 0; j < 4; j++)
                        acc[i][j] = __builtin_amdgcn_mfma_f32_16x16x32_f16(
                            a[i], b[j], acc[i][j], 0, 0, 0);
            }
        }

        // epilogue: C + rank2 -> Bs tile [64][128], then coalesced sc1 stores
        __syncthreads();
        #pragma unroll
        for (int i = 0; i < 2; i++) {
            #pragma unroll
            for (int rr = 0; rr < 4; rr++) {
                int mrow = wr + i * 16 + quad * 4 + rr;
                int m = m0 + mrow;
                float a0 = act[((size_t)m * F_SZ + t) * 2 + 0];
                float a1 = act[((size_t)m * F_SZ + t) * 2 + 1];
                #pragma unroll
                for (int j = 0; j < 4; j++)
                    Bs[mrow * 128 + wc + j * 16 + lrow] =
                        (f16)(acc[i][j][rr] + a0 * mx0[j] + a1 * mx1[j]);
            }
        }
        __syncthreads();
        {
            u64* dst = (u64*)(parts + (size_t)(m0 + erow) * N3 + n0 + eseg);
            const u64* srcl = (const u64*)&Bs[erow * 128 + eseg];
            #pragma unroll
            for (int e = 0; e < 8; e++)
                __hip_atomic_store(dst + e, srcl[e], __ATOMIC_RELAXED, AGENT);
        }
        __syncthreads();                  // drain sc1 stores (vmcnt 0)
        if (tid == 0)
            __hip_atomic_fetch_add(gcnt, 1, __ATOMIC_RELEASE, AGENT);

        // wait: all 24 gemm tiles of group M done (parts rows M final)
        if (tid == 0) {
            int tgt = 24 * (t + 1);
            while (__hip_atomic_load(gcnt, __ATOMIC_RELAXED, AGENT) < tgt)
                __builtin_amdgcn_s_sleep(2);
        }
        __syncthreads();

        // LN + gates: wave handles one full row (64 lanes x 48 values)
        if (doLN) {
            const int row = lnrow;
            const f16* prow = parts + (size_t)row * N3;
            const int l = lane;
            float v[48];
            float s = 0.f, ss = 0.f;
            #pragma unroll
            for (int gte = 0; gte < 3; gte++) {
                #pragma unroll
                for (int q = 0; q < 4; q++) {
                    u64 raw = __hip_atomic_load(
                        (const u64*)(prow + gte * S_SZ + q * 256 + l * 4),
                        __ATOMIC_RELAXED, AGENT);
                    f16x4 xv = __builtin_bit_cast(f16x4, raw);
                    #pragma unroll
                    for (int e = 0; e < 4; e++) {
                        float f = (float)xv[e];
                        v[gte * 16 + q * 4 + e] = f;
                        s += f; ss += f * f;
                    }
                }
            }
            #pragma unroll
            for (int o = 1; o < 64; o <<= 1) {
                s  += __shfl_xor(s, o);
                ss += __shfl_xor(ss, o);
            }
            float mean = s * (1.f / N3);
            float var  = ss * (1.f / N3) - mean * mean;
            float rstd = rsqrtf(var + 1e-3f);
            #pragma unroll
            for (int q = 0; q < 4; q++) {
                int off = q * 256 + l * 4;
                f32x4 gr = *(const f32x4*)(gamma + off);
                f32x4 gc = *(const f32x4*)(gamma + S_SZ + off);
                f32x4 gu = *(const f32x4*)(gamma + 2 * S_SZ + off);
                f32x4 br = *(const f32x4*)(beta + off);
                f32x4 bc = *(const f32x4*)(beta + S_SZ + off);
                f32x4 bu = *(const f32x4*)(beta + 2 * S_SZ + off);
                u64 rawp = __hip_atomic_load(
                    (const u64*)(hh + (size_t)row * S_SZ + off),
                    __ATOMIC_RELAXED, AGENT);
                f16x4 hp4 = __builtin_bit_cast(f16x4, rawp);
                f32x4 hn; f16x4 hs;
                #pragma unroll
                for (int e = 0; e < 4; e++) {
                    int k = q * 4 + e;
                    float nr = (v[k]      - mean) * rstd * gr[e] + br[e];
                    float nc = (v[16 + k] - mean) * rstd * gc[e] + bc[e];
                    float nu = (v[32 + k] - mean) * rstd * gu[e] + bu[e];
                    float rg = 1.f / (1.f + __expf(-nr));
                    float cg = tanhf(rg * nc);
                    float ug = 1.f / (1.f + __expf(-(nu - 1.f)));
                    float hv = ug * cg + (1.f - ug) * (float)hp4[e];
                    hn[e] = hv; hs[e] = (f16)hv;
                }
                __hip_atomic_store((u64*)(hh + (size_t)row * S_SZ + off),
                                   __builtin_bit_cast(u64, hs),
                                   __ATOMIC_RELAXED, AGENT);
                if (t == F_SZ - 1)
                    *(f32x4*)(hout + (size_t)row * S_SZ + off) = hn;
            }
        }
        __syncthreads();                  // drain LN stores
        if (doLN && tid == 0)
            __hip_atomic_fetch_add(dcnt, 1, __ATOMIC_RELEASE, AGENT);
    }
}

// ---------------------------------------------------------------------------
// out[B*S + row*2 + {0,1}] = h_row @ W_dec + b_dec   (fp32)
__global__ __launch_bounds__(256) void final_out(
    const float* __restrict__ h, const float* __restrict__ Wd,
    const float* __restrict__ bd, float* __restrict__ out)
{
    int row = blockIdx.x * 4 + (threadIdx.x >> 6);
    int lane = threadIdx.x & 63;
    const float* hr = h + (size_t)row * S_SZ;
    float s0 = 0.f, s1 = 0.f;
    #pragma unroll
    for (int k = lane; k < S_SZ; k += 64) {
        float x = hr[k];
        s0 += x * Wd[k * 2];
        s1 += x * Wd[k * 2 + 1];
    }
    #pragma unroll
    for (int o = 32; o > 0; o >>= 1) {
        s0 += __shfl_down(s0, o);
        s1 += __shfl_down(s1, o);
    }
    if (lane == 0) {
        out[(size_t)B_SZ * S_SZ + row * 2 + 0] = s0 + bd[0];
        out[(size_t)B_SZ * S_SZ + row * 2 + 1] = s1 + bd[1];
    }
}

// ---------------------------------------------------------------------------
extern "C" void kernel_launch(void* const* d_in, const int* in_sizes, int n_in,
                              void* d_out, int out_size, void* d_ws, size_t ws_size,
                              hipStream_t stream)
{
    const float* act = (const float*)d_in[0]; // [2048][50][2]
    const float* We  = (const float*)d_in[1]; // [2][1024]
    const float* Wg  = (const float*)d_in[2]; // [2048][3072]
    const float* lng = (const float*)d_in[3]; // [3072]
    const float* lnb = (const float*)d_in[4]; // [3072]
    const float* Wd  = (const float*)d_in[5]; // [1024][2]
    const float* bd  = (const float*)d_in[6]; // [2]
    float* out = (float*)d_out;               // fp32 [B*S h_last][B*2 outputs]

    char* ws = (char*)d_ws;                   // ws_size = 256 MiB (measured)
    f16*   Wt    = (f16*)ws;                  // 6,291,456 B
    float* Mx    = (float*)(ws + 6291456);    //    24,576 B
    f16*   hh    = (f16*)(ws + 6316032);      // 4,194,304 B fp16 state
    f16*   parts = (f16*)(ws + 10510336);     // 12,582,912 B
    int*   cnt   = (int*)(ws + 23093248);     //     4,096 B semaphores

    hipMemsetAsync(hh, 0, (size_t)B_SZ * S_SZ * 2, stream);
    hipMemsetAsync(Mx, 0, 2 * N3 * 4, stream);
    hipMemsetAsync(cnt, 0, 4096, stream);
    make_mx<<<dim3(N3 / 256, 16), 256, 0, stream>>>(We, Wg, Mx);
    transpose_w<<<dim3(N3 / 32, S_SZ / 32), 256, 0, stream>>>(Wg, Wt);

    void* kargs[] = {(void*)&Wt, (void*)&hh, (void*)&Mx, (void*)&act,
                     (void*)&lng, (void*)&lnb, (void*)&parts, (void*)&out,
                     (void*)&cnt};
    hipError_t e = hipLaunchCooperativeKernel((void*)fused_loop, dim3(GRID),
                                              dim3(256), kargs, 0, stream);
    if (e != hipSuccess)   // capture/coop unsupported: 768 blocks @3/CU are
        fused_loop<<<GRID, 256, 0, stream>>>(  // co-resident by construction
            Wt, hh, Mx, act, lng, lnb, parts, out, cnt);

    final_out<<<B_SZ / 4, 256, 0, stream>>>(out, Wd, bd, out);
}

// Round 7
// 1678.149 us; speedup vs baseline: 2.4932x; 2.4932x over previous
//
#include <hip/hip_runtime.h>

typedef unsigned short u16;
typedef unsigned int   u32;
typedef unsigned long long u64;
typedef _Float16       f16;

#define B_SZ 2048
#define S_SZ 1024
#define N3   3072
#define F_SZ 50

typedef f16    f16x8 __attribute__((ext_vector_type(8)));
typedef f16    f16x4 __attribute__((ext_vector_type(4)));
typedef float  f32x4 __attribute__((ext_vector_type(4)));
typedef u32    u32x4 __attribute__((ext_vector_type(4)));

// async global->LDS, 16B per lane; LDS dest = base + lane*16 (wave-uniform base)
__device__ __forceinline__ void glds16(const void* g, void* l) {
    __builtin_amdgcn_global_load_lds(
        (const __attribute__((address_space(1))) u32*)g,
        (__attribute__((address_space(3))) u32*)l, 16, 0, 0);
}

// ---------------------------------------------------------------------------
// Mx[2][3072] = W_emb @ W_gru[0:1024, :]  (split-K + atomics; Mx pre-zeroed)
__global__ __launch_bounds__(256) void make_mx(
    const float* __restrict__ We, const float* __restrict__ Wg,
    float* __restrict__ Mx)
{
    int j  = blockIdx.x * 256 + threadIdx.x;
    int k0 = blockIdx.y * 64;
    float s0 = 0.f, s1 = 0.f;
    #pragma unroll 4
    for (int k = k0; k < k0 + 64; k++) {
        float w = Wg[(size_t)k * N3 + j];
        s0 += We[k] * w;
        s1 += We[S_SZ + k] * w;
    }
    atomicAdd(&Mx[j], s0);
    atomicAdd(&Mx[N3 + j], s1);
}

// ---------------------------------------------------------------------------
// Wt[n][k] = fp16(W_gru[1024+k][n])
__global__ __launch_bounds__(256) void transpose_w(
    const float* __restrict__ Wg, f16* __restrict__ Wt)
{
    __shared__ float tile[32][33];
    int n0 = blockIdx.x * 32, k0 = blockIdx.y * 32;
    int c = threadIdx.x & 31, r = threadIdx.x >> 5;
    #pragma unroll
    for (int s = 0; s < 4; s++) {
        int rr = r + s * 8;
        tile[rr][c] = Wg[(size_t)(S_SZ + k0 + rr) * N3 + n0 + c];
    }
    __syncthreads();
    #pragma unroll
    for (int s = 0; s < 4; s++) {
        int rr = r + s * 8;
        Wt[(size_t)(n0 + rr) * S_SZ + k0 + c] = (f16)tile[c][rr];
    }
}

// ---------------------------------------------------------------------------
// 64x128 tile, BK=128, glds16 staging (A and B), XOR-swizzled unpadded LDS.
// Grid 768 1-D with XCD swizzle: each XCD sees 3 NB slices (768 KB of Wt,
// L2-resident). Coherence across steps via kernel boundaries (no atomics).
// LDS chunk = 4 rows x 128 f16 = 1KB; lane l -> row ch*4 + (l>>4),
// stored granule p = l&15 holds global granule g = p ^ (row&7).
__global__ __launch_bounds__(256, 3) void gemm_step(
    const f16* __restrict__ Wt,    // [3072][1024] fp16
    const f16* __restrict__ hh,    // [2048][1024] fp16 state
    const float* __restrict__ Mx,  // [2][3072]
    const float* __restrict__ act, // [2048][50][2]
    f16* __restrict__ parts,       // [2048][3072] f16
    int t)
{
    __shared__ __align__(16) f16 As[64 * 128];    // 16 KB
    __shared__ __align__(16) f16 Bs[128 * 128];   // 32 KB

    const int blk = blockIdx.x;
    const int x8  = blk & 7;            // XCD hint
    const int r   = blk >> 3;           // 0..95
    const int NB  = x8 * 3 + (r % 3);   // 0..23
    const int M   = r / 3;              // 0..31
    const int m0 = M * 64, n0 = NB * 128;

    const int tid  = threadIdx.x;
    const int lane = tid & 63;
    const int wave = tid >> 6;
    const int wr = (wave >> 1) * 32;
    const int wc = (wave & 1) * 64;
    const int quad = lane >> 4, lrow = lane & 15;
    const int lr7 = lrow & 7;

    // staging lane geometry
    const int srow = lane >> 4;                       // row-in-chunk 0..3
    const int sgrn = (lane & 15);                     // stored granule

    f32x4 acc[2][4];
    #pragma unroll
    for (int i = 0; i < 2; i++)
        #pragma unroll
        for (int j = 0; j < 4; j++)
            acc[i][j] = (f32x4){0.f, 0.f, 0.f, 0.f};

    for (int kb = 0; kb < S_SZ; kb += 128) {
        __syncthreads();
        #pragma unroll
        for (int c = 0; c < 4; c++) {          // A: 16 chunks, 4 per wave
            int ch = wave * 4 + c;
            int row = ch * 4 + srow;
            int g = sgrn ^ (row & 7);
            glds16(&hh[(size_t)(m0 + row) * S_SZ + kb + g * 8], &As[ch * 512]);
        }
        #pragma unroll
        for (int c = 0; c < 8; c++) {          // B: 32 chunks, 8 per wave
            int ch = wave * 8 + c;
            int row = ch * 4 + srow;
            int g = sgrn ^ (row & 7);
            glds16(&Wt[(size_t)(n0 + row) * S_SZ + kb + g * 8], &Bs[ch * 512]);
        }
        __syncthreads();
        #pragma unroll
        for (int kk = 0; kk < 128; kk += 32) {
            f16x8 a[2], b[4];
            int gq = (kk >> 3) + quad;
            #pragma unroll
            for (int i = 0; i < 2; i++)
                a[i] = __builtin_bit_cast(f16x8,
                    *(const u32x4*)&As[(wr + i * 16 + lrow) * 128 +
                                       (gq ^ lr7) * 8]);
            #pragma unroll
            for (int j = 0; j < 4; j++)
                b[j] = __builtin_bit_cast(f16x8,
                    *(const u32x4*)&Bs[(wc + j * 16 + lrow) * 128 +
                                       (gq ^ lr7) * 8]);
            #pragma unroll
            for (int i = 0; i < 2; i++)
                #pragma unroll
                for (int j = 0; j < 4; j++)
                    acc[i][j] = __builtin_amdgcn_mfma_f32_16x16x32_f16(
                        a[i], b[j], acc[i][j], 0, 0, 0);
        }
    }

    #pragma unroll
    for (int i = 0; i < 2; i++) {
        #pragma unroll
        for (int rr = 0; rr < 4; rr++) {
            int m = m0 + wr + i * 16 + quad * 4 + rr;
            float a0 = act[((size_t)m * F_SZ + t) * 2 + 0];
            float a1 = act[((size_t)m * F_SZ + t) * 2 + 1];
            #pragma unroll
            for (int j = 0; j < 4; j++) {
                int n = n0 + wc + j * 16 + lrow;
                parts[(size_t)m * N3 + n] =
                    (f16)(acc[i][j][rr] + a0 * Mx[n] + a1 * Mx[N3 + n]);
            }
        }
    }
}

// ---------------------------------------------------------------------------
// LayerNorm + gates + h update. 2 rows per block; thread owns 8 units.
// h state is fp16-only during the recurrence; fp32 h written to d_out at t=49.
__global__ __launch_bounds__(256) void ln_gate_step(
    const f16* __restrict__ parts,
    const float* __restrict__ gamma,
    const float* __restrict__ beta,
    f16* __restrict__ hh,           // fp16 state
    float* __restrict__ hout,       // d_out h region (written only at t=49)
    int t)
{
    const int tid = threadIdx.x;
    const int r2  = tid >> 7;                 // 0..1
    const int tl  = tid & 127;                // 0..127, owns units tl*8..tl*8+7
    const int row = blockIdx.x * 2 + r2;
    const f16* p = parts + (size_t)row * N3 + tl * 8;

    float v[24];
    float s = 0.f, ss = 0.f;
    #pragma unroll
    for (int g = 0; g < 3; g++) {
        f16x8 x = *(const f16x8*)(p + g * S_SZ);
        #pragma unroll
        for (int e = 0; e < 8; e++) {
            float f = (float)x[e];
            v[g * 8 + e] = f;
            s += f; ss += f * f;
        }
    }
    #pragma unroll
    for (int o = 1; o < 64; o <<= 1) {
        s  += __shfl_xor(s, o);
        ss += __shfl_xor(ss, o);
    }
    __shared__ float red[8];
    int wave = tid >> 6, lane = tid & 63;
    if (lane == 0) { red[wave] = s; red[4 + wave] = ss; }
    __syncthreads();
    float S  = red[r2 * 2] + red[r2 * 2 + 1];
    float SS = red[4 + r2 * 2] + red[4 + r2 * 2 + 1];
    float mean = S * (1.f / N3);
    float var  = SS * (1.f / N3) - mean * mean;
    float rstd = rsqrtf(var + 1e-3f);

    float nv[24];
    #pragma unroll
    for (int g = 0; g < 3; g++) {
        f32x4 g0 = *(const f32x4*)(gamma + g * S_SZ + tl * 8);
        f32x4 g1 = *(const f32x4*)(gamma + g * S_SZ + tl * 8 + 4);
        f32x4 b0 = *(const f32x4*)(beta  + g * S_SZ + tl * 8);
        f32x4 b1 = *(const f32x4*)(beta  + g * S_SZ + tl * 8 + 4);
        #pragma unroll
        for (int e = 0; e < 4; e++) {
            nv[g * 8 + e]     = (v[g * 8 + e]     - mean) * rstd * g0[e] + b0[e];
            nv[g * 8 + e + 4] = (v[g * 8 + e + 4] - mean) * rstd * g1[e] + b1[e];
        }
    }

    size_t hbase = (size_t)row * S_SZ + tl * 8;
    f16x8 hp = *(const f16x8*)(hh + hbase);
    f16x8 hs;
    f32x4 ho0, ho1;
    #pragma unroll
    for (int e = 0; e < 8; e++) {
        float rg = 1.f / (1.f + __expf(-nv[e]));
        float cg = tanhf(rg * nv[8 + e]);
        float ug = 1.f / (1.f + __expf(-(nv[16 + e] - 1.f)));
        float hv = ug * cg + (1.f - ug) * (float)hp[e];
        hs[e] = (f16)hv;
        if (e < 4) ho0[e] = hv; else ho1[e - 4] = hv;
    }
    *(f16x8*)(hh + hbase) = hs;
    if (t == F_SZ - 1) {
        *(f32x4*)(hout + hbase)     = ho0;
        *(f32x4*)(hout + hbase + 4) = ho1;
    }
}

// ---------------------------------------------------------------------------
// out[B*S + row*2 + {0,1}] = h_row @ W_dec + b_dec   (fp32)
__global__ __launch_bounds__(256) void final_out(
    const float* __restrict__ h, const float* __restrict__ Wd,
    const float* __restrict__ bd, float* __restrict__ out)
{
    int row = blockIdx.x * 4 + (threadIdx.x >> 6);
    int lane = threadIdx.x & 63;
    const float* hr = h + (size_t)row * S_SZ;
    float s0 = 0.f, s1 = 0.f;
    #pragma unroll
    for (int k = lane; k < S_SZ; k += 64) {
        float x = hr[k];
        s0 += x * Wd[k * 2];
        s1 += x * Wd[k * 2 + 1];
    }
    #pragma unroll
    for (int o = 32; o > 0; o >>= 1) {
        s0 += __shfl_down(s0, o);
        s1 += __shfl_down(s1, o);
    }
    if (lane == 0) {
        out[(size_t)B_SZ * S_SZ + row * 2 + 0] = s0 + bd[0];
        out[(size_t)B_SZ * S_SZ + row * 2 + 1] = s1 + bd[1];
    }
}

// ---------------------------------------------------------------------------
extern "C" void kernel_launch(void* const* d_in, const int* in_sizes, int n_in,
                              void* d_out, int out_size, void* d_ws, size_t ws_size,
                              hipStream_t stream)
{
    const float* act = (const float*)d_in[0]; // [2048][50][2]
    const float* We  = (const float*)d_in[1]; // [2][1024]
    const float* Wg  = (const float*)d_in[2]; // [2048][3072]
    const float* lng = (const float*)d_in[3]; // [3072]
    const float* lnb = (const float*)d_in[4]; // [3072]
    const float* Wd  = (const float*)d_in[5]; // [1024][2]
    const float* bd  = (const float*)d_in[6]; // [2]
    float* out = (float*)d_out;               // fp32 [B*S h_last][B*2 outputs]

    char* ws = (char*)d_ws;                   // ws_size = 256 MiB (measured)
    f16*   Wt    = (f16*)ws;                  //  6,291,456 B
    float* Mx    = (float*)(ws + 6291456);    //     24,576 B
    f16*   hh    = (f16*)(ws + 6316032);      //  4,194,304 B fp16 state
    f16*   parts = (f16*)(ws + 10510336);     // 12,582,912 B

    hipMemsetAsync(hh, 0, (size_t)B_SZ * S_SZ * 2, stream);
    hipMemsetAsync(Mx, 0, 2 * N3 * 4, stream);
    make_mx<<<dim3(N3 / 256, 16), 256, 0, stream>>>(We, Wg, Mx);
    transpose_w<<<dim3(N3 / 32, S_SZ / 32), 256, 0, stream>>>(Wg, Wt);

    for (int t = 0; t < F_SZ; t++) {
        gemm_step<<<768, 256, 0, stream>>>(Wt, hh, Mx, act, parts, t);
        ln_gate_step<<<B_SZ / 2, 256, 0, stream>>>(parts, lng, lnb, hh, out, t);
    }
    final_out<<<B_SZ / 4, 256, 0, stream>>>(out, Wd, bd, out);
}

// Round 8
// 1442.390 us; speedup vs baseline: 2.9007x; 1.1635x over previous
//
#include <hip/hip_runtime.h>

typedef unsigned short u16;
typedef unsigned int   u32;
typedef _Float16       f16;

#define B_SZ 2048
#define S_SZ 1024
#define N3   3072
#define F_SZ 50

typedef f16    f16x8 __attribute__((ext_vector_type(8)));
typedef f16    f16x4 __attribute__((ext_vector_type(4)));
typedef float  f32x4 __attribute__((ext_vector_type(4)));
typedef u32    u32x4 __attribute__((ext_vector_type(4)));

// async global->LDS, 16B per lane; LDS dest = base + lane*16 (wave-uniform base)
__device__ __forceinline__ void glds16(const void* g, void* l) {
    __builtin_amdgcn_global_load_lds(
        (const __attribute__((address_space(1))) u32*)g,
        (__attribute__((address_space(3))) u32*)l, 16, 0, 0);
}

// ---------------------------------------------------------------------------
// Mx[2][3072] = W_emb @ W_gru[0:1024, :]  (split-K + atomics; Mx pre-zeroed)
__global__ __launch_bounds__(256) void make_mx(
    const float* __restrict__ We, const float* __restrict__ Wg,
    float* __restrict__ Mx)
{
    int j  = blockIdx.x * 256 + threadIdx.x;
    int k0 = blockIdx.y * 64;
    float s0 = 0.f, s1 = 0.f;
    #pragma unroll 4
    for (int k = k0; k < k0 + 64; k++) {
        float w = Wg[(size_t)k * N3 + j];
        s0 += We[k] * w;
        s1 += We[S_SZ + k] * w;
    }
    atomicAdd(&Mx[j], s0);
    atomicAdd(&Mx[N3 + j], s1);
}

// ---------------------------------------------------------------------------
// Wt[n][k] = fp16(W_gru[1024+k][n])
__global__ __launch_bounds__(256) void transpose_w(
    const float* __restrict__ Wg, f16* __restrict__ Wt)
{
    __shared__ float tile[32][33];
    int n0 = blockIdx.x * 32, k0 = blockIdx.y * 32;
    int c = threadIdx.x & 31, r = threadIdx.x >> 5;
    #pragma unroll
    for (int s = 0; s < 4; s++) {
        int rr = r + s * 8;
        tile[rr][c] = Wg[(size_t)(S_SZ + k0 + rr) * N3 + n0 + c];
    }
    __syncthreads();
    #pragma unroll
    for (int s = 0; s < 4; s++) {
        int rr = r + s * 8;
        Wt[(size_t)(n0 + rr) * S_SZ + k0 + c] = (f16)tile[c][rr];
    }
}

// ---------------------------------------------------------------------------
// 64x128 tile, BK=64, glds16 staging, XOR-swizzled unpadded LDS.
// (R5 structure verbatim — measured best: BK=128 regressed 6.5 us/step (R7),
//  persistence regressed 2.8x (R6). Grid dim3(32,24), no XCD swizzle.)
__global__ __launch_bounds__(256) void gemm_step(
    const f16* __restrict__ Wt,    // [3072][1024] fp16
    const f16* __restrict__ hh,    // [2048][1024] fp16 state
    const float* __restrict__ Mx,  // [2][3072]
    const float* __restrict__ act, // [2048][50][2]
    f16* __restrict__ parts,       // [2048][3072] f16
    int t)
{
    __shared__ __align__(16) f16 As[64 * 64];    // 8 KB
    __shared__ __align__(16) f16 Bs[128 * 64];   // 16 KB
    const int m0 = blockIdx.x * 64;
    const int n0 = blockIdx.y * 128;
    const int tid  = threadIdx.x;
    const int lane = tid & 63;
    const int wave = tid >> 6;
    const int wr = (wave >> 1) * 32;   // wave row offset (A)
    const int wc = (wave & 1) * 64;    // wave col offset (B)
    const int quad = lane >> 4, lrow = lane & 15;
    const int swz = (lrow & 7) * 8;

    // staging lane geometry: 8 rows x 64 halves per 1KB chunk
    const int lrow8 = lane >> 3;
    const int scolh = ((lane & 7) * 8) ^ (lrow8 * 8);  // swizzled source col

    f32x4 acc[2][4];
    #pragma unroll
    for (int i = 0; i < 2; i++)
        #pragma unroll
        for (int j = 0; j < 4; j++)
            acc[i][j] = (f32x4){0.f, 0.f, 0.f, 0.f};

    for (int kb = 0; kb < S_SZ; kb += 64) {
        __syncthreads();
        #pragma unroll
        for (int c = 0; c < 2; c++) {          // A: 8 chunks, 2 per wave
            int ch = wave * 2 + c;
            int row = ch * 8 + lrow8;
            glds16(&hh[(size_t)(m0 + row) * S_SZ + kb + scolh], &As[ch * 512]);
        }
        #pragma unroll
        for (int c = 0; c < 4; c++) {          // B: 16 chunks, 4 per wave
            int ch = wave * 4 + c;
            int row = ch * 8 + lrow8;
            glds16(&Wt[(size_t)(n0 + row) * S_SZ + kb + scolh], &Bs[ch * 512]);
        }
        __syncthreads();
        #pragma unroll
        for (int kk = 0; kk < 64; kk += 32) {
            f16x8 a[2], b[4];
            #pragma unroll
            for (int i = 0; i < 2; i++)
                a[i] = __builtin_bit_cast(f16x8,
                    *(const u32x4*)&As[(wr + i * 16 + lrow) * 64 +
                                       ((kk + quad * 8) ^ swz)]);
            #pragma unroll
            for (int j = 0; j < 4; j++)
                b[j] = __builtin_bit_cast(f16x8,
                    *(const u32x4*)&Bs[(wc + j * 16 + lrow) * 64 +
                                       ((kk + quad * 8) ^ swz)]);
            #pragma unroll
            for (int i = 0; i < 2; i++)
                #pragma unroll
                for (int j = 0; j < 4; j++)
                    acc[i][j] = __builtin_amdgcn_mfma_f32_16x16x32_f16(
                        a[i], b[j], acc[i][j], 0, 0, 0);
        }
    }

    #pragma unroll
    for (int i = 0; i < 2; i++) {
        #pragma unroll
        for (int rr = 0; rr < 4; rr++) {
            int m = m0 + wr + i * 16 + quad * 4 + rr;
            float a0 = act[((size_t)m * F_SZ + t) * 2 + 0];
            float a1 = act[((size_t)m * F_SZ + t) * 2 + 1];
            #pragma unroll
            for (int j = 0; j < 4; j++) {
                int n = n0 + wc + j * 16 + lrow;
                parts[(size_t)m * N3 + n] =
                    (f16)(acc[i][j][rr] + a0 * Mx[n] + a1 * Mx[N3 + n]);
            }
        }
    }
}

// ---------------------------------------------------------------------------
// LayerNorm + gates + h update. 2 rows/block; thread owns 8 units (R7 slim).
// h state fp16-only during recurrence; fp32 h written to d_out at t=49.
__global__ __launch_bounds__(256) void ln_gate_step(
    const f16* __restrict__ parts,
    const float* __restrict__ gamma,
    const float* __restrict__ beta,
    f16* __restrict__ hh,           // fp16 state
    float* __restrict__ hout,       // d_out h region (written only at t=49)
    int t)
{
    const int tid = threadIdx.x;
    const int r2  = tid >> 7;                 // 0..1
    const int tl  = tid & 127;                // owns units tl*8..tl*8+7
    const int row = blockIdx.x * 2 + r2;
    const f16* p = parts + (size_t)row * N3 + tl * 8;

    float v[24];
    float s = 0.f, ss = 0.f;
    #pragma unroll
    for (int g = 0; g < 3; g++) {
        f16x8 x = *(const f16x8*)(p + g * S_SZ);
        #pragma unroll
        for (int e = 0; e < 8; e++) {
            float f = (float)x[e];
            v[g * 8 + e] = f;
            s += f; ss += f * f;
        }
    }
    #pragma unroll
    for (int o = 1; o < 64; o <<= 1) {
        s  += __shfl_xor(s, o);
        ss += __shfl_xor(ss, o);
    }
    __shared__ float red[8];
    int wave = tid >> 6, lane = tid & 63;
    if (lane == 0) { red[wave] = s; red[4 + wave] = ss; }
    __syncthreads();
    float S  = red[r2 * 2] + red[r2 * 2 + 1];
    float SS = red[4 + r2 * 2] + red[4 + r2 * 2 + 1];
    float mean = S * (1.f / N3);
    float var  = SS * (1.f / N3) - mean * mean;
    float rstd = rsqrtf(var + 1e-3f);

    float nv[24];
    #pragma unroll
    for (int g = 0; g < 3; g++) {
        f32x4 g0 = *(const f32x4*)(gamma + g * S_SZ + tl * 8);
        f32x4 g1 = *(const f32x4*)(gamma + g * S_SZ + tl * 8 + 4);
        f32x4 b0 = *(const f32x4*)(beta  + g * S_SZ + tl * 8);
        f32x4 b1 = *(const f32x4*)(beta  + g * S_SZ + tl * 8 + 4);
        #pragma unroll
        for (int e = 0; e < 4; e++) {
            nv[g * 8 + e]     = (v[g * 8 + e]     - mean) * rstd * g0[e] + b0[e];
            nv[g * 8 + e + 4] = (v[g * 8 + e + 4] - mean) * rstd * g1[e] + b1[e];
        }
    }

    size_t hbase = (size_t)row * S_SZ + tl * 8;
    f16x8 hp = *(const f16x8*)(hh + hbase);
    f16x8 hs;
    f32x4 ho0, ho1;
    #pragma unroll
    for (int e = 0; e < 8; e++) {
        float rg = 1.f / (1.f + __expf(-nv[e]));
        float x  = rg * nv[8 + e];
        float tt = __expf(-2.f * fabsf(x));            // stable fast tanh
        float cg = __builtin_copysignf((1.f - tt) / (1.f + tt), x);
        float ug = 1.f / (1.f + __expf(-(nv[16 + e] - 1.f)));
        float hv = ug * cg + (1.f - ug) * (float)hp[e];
        hs[e] = (f16)hv;
        if (e < 4) ho0[e] = hv; else ho1[e - 4] = hv;
    }
    *(f16x8*)(hh + hbase) = hs;
    if (t == F_SZ - 1) {
        *(f32x4*)(hout + hbase)     = ho0;
        *(f32x4*)(hout + hbase + 4) = ho1;
    }
}

// ---------------------------------------------------------------------------
// out[B*S + row*2 + {0,1}] = h_row @ W_dec + b_dec   (fp32)
__global__ __launch_bounds__(256) void final_out(
    const float* __restrict__ h, const float* __restrict__ Wd,
    const float* __restrict__ bd, float* __restrict__ out)
{
    int row = blockIdx.x * 4 + (threadIdx.x >> 6);
    int lane = threadIdx.x & 63;
    const float* hr = h + (size_t)row * S_SZ;
    float s0 = 0.f, s1 = 0.f;
    #pragma unroll
    for (int k = lane; k < S_SZ; k += 64) {
        float x = hr[k];
        s0 += x * Wd[k * 2];
        s1 += x * Wd[k * 2 + 1];
    }
    #pragma unroll
    for (int o = 32; o > 0; o >>= 1) {
        s0 += __shfl_down(s0, o);
        s1 += __shfl_down(s1, o);
    }
    if (lane == 0) {
        out[(size_t)B_SZ * S_SZ + row * 2 + 0] = s0 + bd[0];
        out[(size_t)B_SZ * S_SZ + row * 2 + 1] = s1 + bd[1];
    }
}

// ---------------------------------------------------------------------------
extern "C" void kernel_launch(void* const* d_in, const int* in_sizes, int n_in,
                              void* d_out, int out_size, void* d_ws, size_t ws_size,
                              hipStream_t stream)
{
    const float* act = (const float*)d_in[0]; // [2048][50][2]
    const float* We  = (const float*)d_in[1]; // [2][1024]
    const float* Wg  = (const float*)d_in[2]; // [2048][3072]
    const float* lng = (const float*)d_in[3]; // [3072]
    const float* lnb = (const float*)d_in[4]; // [3072]
    const float* Wd  = (const float*)d_in[5]; // [1024][2]
    const float* bd  = (const float*)d_in[6]; // [2]
    float* out = (float*)d_out;               // fp32 [B*S h_last][B*2 outputs]

    char* ws = (char*)d_ws;                   // ws_size = 256 MiB (measured)
    f16*   Wt    = (f16*)ws;                  //  6,291,456 B
    float* Mx    = (float*)(ws + 6291456);    //     24,576 B
    f16*   hh    = (f16*)(ws + 6316032);      //  4,194,304 B fp16 state
    f16*   parts = (f16*)(ws + 10510336);     // 12,582,912 B

    hipMemsetAsync(hh, 0, (size_t)B_SZ * S_SZ * 2, stream);
    hipMemsetAsync(Mx, 0, 2 * N3 * 4, stream);
    make_mx<<<dim3(N3 / 256, 16), 256, 0, stream>>>(We, Wg, Mx);
    transpose_w<<<dim3(N3 / 32, S_SZ / 32), 256, 0, stream>>>(Wg, Wt);

    for (int t = 0; t < F_SZ; t++) {
        gemm_step<<<dim3(32, 24), 256, 0, stream>>>(Wt, hh, Mx, act, parts, t);
        ln_gate_step<<<B_SZ / 2, 256, 0, stream>>>(parts, lng, lnb, hh, out, t);
    }
    final_out<<<B_SZ / 4, 256, 0, stream>>>(out, Wd, bd, out);
}